// Round 9
// baseline (194.306 us; speedup 1.0000x reference)
//
#include <hip/hip_runtime.h>
#include <math.h>

#define BB 4096
#define LL 50
#define NN 50
#define DD 128
#define STR 136    // bf16 LDS row stride in shorts (272 B: odd 4-bank rotation/row)
#define NB 8       // batches per block
#define GRID 512   // 4096 / NB  (exactly 2 blocks/CU)

typedef short bf16x8 __attribute__((ext_vector_type(8)));   // 8 bf16 = 4 VGPRs
typedef float f32x4  __attribute__((ext_vector_type(4)));

#define AS1 __attribute__((address_space(1)))
#define AS3 __attribute__((address_space(3)))

static __device__ inline unsigned short f32_to_bf16_rne(float f) {
    unsigned int u = __float_as_uint(f);
    u += 0x7FFFu + ((u >> 16) & 1u);   // round-nearest-even
    return (unsigned short)(u >> 16);
}
static __device__ inline float bf16_to_f32(unsigned short h) {
    return __uint_as_float(((unsigned int)h) << 16);
}

// Combined B fragments for mfma_f32_16x16x32_bf16 over extended K=256:
//   kk 0..3 -> W_seq rows, kk 4..7 -> W_last rows.
// ws[((kk*8+nt)*64+lane)*8+j] = W[(kk&3)*32+(lane>>4)*8+j][nt*16+(lane&15)]
__global__ void prep_w(const float* __restrict__ W_seq,
                       const float* __restrict__ W_last,
                       unsigned short* __restrict__ ws)
{
    int t = blockIdx.x * blockDim.x + threadIdx.x;   // 0..4095
    int lane = t & 63;
    int nt   = (t >> 6) & 7;
    int kk   = t >> 9;
    const float* W = (kk < 4) ? W_seq : W_last;
    int kb = (kk & 3) * 32 + (lane >> 4) * 8;
    int n  = nt * 16 + (lane & 15);
    unsigned short* dst = ws + (size_t)t * 8;
    #pragma unroll
    for (int j = 0; j < 8; ++j)
        dst[j] = f32_to_bf16_rne(W[(kb + j) * DD + n]);
}

// 512 persistent-ish blocks x 256 threads (4 waves), 8 batches per block,
// software-pipelined: while batch i computes from the double-buffered bf16
// tile, the global_load_lds volley for tile i+1 streams into the f32 staging
// buffer (freed by the convert phase). Mask/seq for all 8 batches are loaded
// in ONE coalesced volley at t=0 and reduced in the prologue, so no HBM
// latency sits inside the per-batch chain. Rationale (R0-R8 evidence): every
// non-pipelined structure converged to 52-64us with NOTHING busy (R7: occ
// 67%, VALU 38%, Mfma 10%, HBM 11%) — the convoy of [load tile -> compute]
// left memory idle half the time. Steady-state here: per-CU memory stays
// continuously fed (2 blocks x 25.6KB in flight >> 10KB BDP).
__global__ __launch_bounds__(256, 2) void sess_attn(
    const int*   __restrict__ seq_idx,   // [B,L]
    const int*   __restrict__ mask,      // [B,L]
    const float* __restrict__ nodes,     // [B,N,D]
    const float* __restrict__ b_seq,     // [D]
    const float* __restrict__ W_alpha,   // [D]
    const unsigned short* __restrict__ wfrag,  // d_ws, combined B-frags
    float*       __restrict__ out)       // [B*D] v_n, then [B*D] session_graph
{
    const int blk  = blockIdx.x;
    const int tid  = threadIdx.x;
    const int lane = tid & 63;
    const int wave = tid >> 6;
    const int col  = lane & 15;
    const int quad = lane >> 4;

    __shared__ __align__(16) float          s_f[NN * DD];        // 25600 B DMA dest
    __shared__ __align__(16) unsigned short s_nbf[2][NN * STR];  // 2x13600 B
    __shared__ float s_alpha[2][64];
    __shared__ float s_cnt[NB][64];
    __shared__ __align__(16) int s_mask[NB * LL];
    __shared__ __align__(16) int s_sidx[NB * LL];
    __shared__ int   s_last[NB];

    const int b0 = blk * NB;

    // ---- prologue: mask/seq volley (oldest vmcnt slots), then DMA(b0). ----
    int4 m4, s4;
    if (tid < 100) {
        m4 = ((const int4*)(mask    + b0 * LL))[tid];   // 400 ints = 100 int4
        s4 = ((const int4*)(seq_idx + b0 * LL))[tid];
    }

    {   // DMA tile 0: 1600 float4, linear; wave-uniform LDS bases (m104/m108)
        const float* nb = nodes + (size_t)b0 * (NN * DD);
        #pragma unroll
        for (int c = 0; c < 6; ++c)
            __builtin_amdgcn_global_load_lds(
                (const AS1 unsigned int*)(nb + (size_t)(c * 256 + tid) * 4),
                (AS3 unsigned int*)(&s_f[(c * 256 + wave * 64) * 4]), 16, 0, 0);
        if (tid < 64)
            __builtin_amdgcn_global_load_lds(
                (const AS1 unsigned int*)(nb + (size_t)(1536 + tid) * 4),
                (AS3 unsigned int*)(&s_f[1536 * 4]), 16, 0, 0);
    }

    // B fragments (L2-resident) + epilogue scalars for this wave's n-tiles.
    const bf16x8* wsf = (const bf16x8*)wfrag;
    bf16x8 bfS[8], bfL[8];
    #pragma unroll
    for (int kk = 0; kk < 4; ++kk)
        #pragma unroll
        for (int j2 = 0; j2 < 2; ++j2) {
            bfS[kk * 2 + j2] = wsf[(size_t)(((kk    ) * 8 + wave * 2 + j2) * 64 + lane)];
            bfL[kk * 2 + j2] = wsf[(size_t)(((kk + 4) * 8 + wave * 2 + j2) * 64 + lane)];
        }
    float bb_r[2], wa_r[2];
    #pragma unroll
    for (int j2 = 0; j2 < 2; ++j2) {
        int n = (wave * 2 + j2) * 16 + col;
        bb_r[j2] = b_seq[n];
        wa_r[j2] = W_alpha[n];
    }

    // zero cnt (8 arrays) + both alpha parities; park mask volley in LDS.
    #pragma unroll
    for (int z = 0; z < 2; ++z) s_cnt[z * 4 + wave][lane] = 0.f;
    if (tid < 64) { s_alpha[0][tid] = 0.f; s_alpha[1][tid] = 0.f; }
    if (tid < 100) {
        *(int4*)&s_mask[tid * 4] = m4;
        *(int4*)&s_sidx[tid * 4] = s4;
    }

    __syncthreads();   // masks in LDS; cnt/alpha zeroed; DMA(0) drained

    // ---- all 8 histograms / last-indices up front (wave w: batches 2w,2w+1).
    #pragma unroll
    for (int t2 = 0; t2 < 2; ++t2) {
        int ib = wave * 2 + t2;
        int pm = (lane < LL) ? s_mask[ib * LL + lane] : 0;
        int pi = (lane < LL) ? s_sidx[ib * LL + lane] : 0;
        int mm = pm;
        mm += __shfl_xor(mm, 1);  mm += __shfl_xor(mm, 2);
        mm += __shfl_xor(mm, 4);  mm += __shfl_xor(mm, 8);
        mm += __shfl_xor(mm, 16); mm += __shfl_xor(mm, 32);
        int jl = mm - 1;
        if (jl < 0) jl += LL;                 // JAX negative-index wrap
        int li = __shfl(pi, jl);
        if (lane == 0) s_last[ib] = li;
        if (lane < LL && pm) atomicAdd(&s_cnt[ib][pi], (float)pm);
    }

    __syncthreads();   // s_last/s_cnt complete for all batches

    const int r0 = col, r1 = 16 + col, r2 = 32 + col;
    const int r3 = (48 + col > NN - 1) ? (NN - 1) : (48 + col);

    for (int i = 0; i < NB; ++i) {
        const int b   = b0 + i;
        const int par = i & 1;

        // recycle the alpha parity freed by final(i-1) (epilogue(i+1) uses it)
        if (i >= 1 && tid < 64) s_alpha[(i - 1) & 1][tid] = 0.f;

        // ---- convert tile i: f32 staging -> bf16 tile (each element once).
        #pragma unroll
        for (int c = 0; c < 6; ++c) {
            int p = c * 256 + tid;
            int r = p >> 5, cc = (p & 31) * 4;
            float4 f = *(const float4*)&s_f[p * 4];
            ushort4 h;
            h.x = f32_to_bf16_rne(f.x); h.y = f32_to_bf16_rne(f.y);
            h.z = f32_to_bf16_rne(f.z); h.w = f32_to_bf16_rne(f.w);
            *(ushort4*)&s_nbf[par][r * STR + cc] = h;
        }
        if (tid < 64) {
            int p = 1536 + tid;
            int r = p >> 5, cc = (p & 31) * 4;
            float4 f = *(const float4*)&s_f[p * 4];
            ushort4 h;
            h.x = f32_to_bf16_rne(f.x); h.y = f32_to_bf16_rne(f.y);
            h.z = f32_to_bf16_rne(f.z); h.w = f32_to_bf16_rne(f.w);
            *(ushort4*)&s_nbf[par][r * STR + cc] = h;
        }

        __syncthreads();   // bf16 tile i ready; s_f free for reuse

        // ---- issue DMA for tile i+1 NOW; it streams under the compute below.
        if (i < NB - 1) {
            const float* nb = nodes + (size_t)(b + 1) * (NN * DD);
            #pragma unroll
            for (int c = 0; c < 6; ++c)
                __builtin_amdgcn_global_load_lds(
                    (const AS1 unsigned int*)(nb + (size_t)(c * 256 + tid) * 4),
                    (AS3 unsigned int*)(&s_f[(c * 256 + wave * 64) * 4]), 16, 0, 0);
            if (tid < 64)
                __builtin_amdgcn_global_load_lds(
                    (const AS1 unsigned int*)(nb + (size_t)(1536 + tid) * 4),
                    (AS3 unsigned int*)(&s_f[1536 * 4]), 16, 0, 0);
        }

        const int last = s_last[i];

        // v_n output: exact f32; the row is L2-hot (tile i just streamed).
        if (tid < DD)
            out[(size_t)b * DD + tid] =
                nodes[(size_t)b * (NN * DD) + last * DD + tid];

        // ---- MFMA: acc (W_seq) per m-tile; accV (W_last) row-invariant.
        f32x4 acc[4][2], accV[2];
        #pragma unroll
        for (int m = 0; m < 4; ++m)
            #pragma unroll
            for (int j2 = 0; j2 < 2; ++j2)
                acc[m][j2] = (f32x4){0.f, 0.f, 0.f, 0.f};
        #pragma unroll
        for (int j2 = 0; j2 < 2; ++j2)
            accV[j2] = (f32x4){bb_r[j2], bb_r[j2], bb_r[j2], bb_r[j2]};

        const unsigned short* tb = s_nbf[par];
        #pragma unroll
        for (int kk = 0; kk < 4; ++kk) {
            const int co = kk * 32 + quad * 8;
            bf16x8 a0 = *(const bf16x8*)&tb[r0 * STR + co];
            bf16x8 a1 = *(const bf16x8*)&tb[r1 * STR + co];
            bf16x8 a2 = *(const bf16x8*)&tb[r2 * STR + co];
            bf16x8 a3 = *(const bf16x8*)&tb[r3 * STR + co];
            bf16x8 av = *(const bf16x8*)&tb[last * STR + co];
            #pragma unroll
            for (int j2 = 0; j2 < 2; ++j2) {
                acc[0][j2] = __builtin_amdgcn_mfma_f32_16x16x32_bf16(a0, bfS[kk * 2 + j2], acc[0][j2], 0, 0, 0);
                acc[1][j2] = __builtin_amdgcn_mfma_f32_16x16x32_bf16(a1, bfS[kk * 2 + j2], acc[1][j2], 0, 0, 0);
                acc[2][j2] = __builtin_amdgcn_mfma_f32_16x16x32_bf16(a2, bfS[kk * 2 + j2], acc[2][j2], 0, 0, 0);
                acc[3][j2] = __builtin_amdgcn_mfma_f32_16x16x32_bf16(a3, bfS[kk * 2 + j2], acc[3][j2], 0, 0, 0);
                accV[j2]   = __builtin_amdgcn_mfma_f32_16x16x32_bf16(av, bfL[kk * 2 + j2], accV[j2],   0, 0, 0);
            }
        }

        // ---- epilogue: alpha[row] += sum_cols sigmoid(acc+accV)*W_alpha.
        //      C layout: col = lane&15, row = m*16 + quad*4 + r.
        #pragma unroll
        for (int m = 0; m < 4; ++m) {
            float pr[4] = {0.f, 0.f, 0.f, 0.f};
            #pragma unroll
            for (int j2 = 0; j2 < 2; ++j2) {
                float waj = wa_r[j2];
                #pragma unroll
                for (int r = 0; r < 4; ++r) {
                    float x = acc[m][j2][r] + accV[j2][r];
                    pr[r] = fmaf(1.f / (1.f + __expf(-x)), waj, pr[r]);
                }
            }
            #pragma unroll
            for (int r = 0; r < 4; ++r) {
                float vv = pr[r];
                vv += __shfl_xor(vv, 1);
                vv += __shfl_xor(vv, 2);
                vv += __shfl_xor(vv, 4);
                vv += __shfl_xor(vv, 8);
                int row = m * 16 + quad * 4 + r;
                if (col == 0 && row < NN) atomicAdd(&s_alpha[par][row], vv);
            }
        }

        __syncthreads();   // alpha(i) complete (also drains DMA(i+1) tail)

        // ---- session_graph[d] = sum_n cnt[n]*alpha[n]*node_bf16[n][d]. ----
        if (tid < DD) {
            float accA = 0.f, accB = 0.f;
            #pragma unroll 5
            for (int n = 0; n < NN; n += 2) {
                float wA = s_cnt[i][n]     * s_alpha[par][n];
                float wB = s_cnt[i][n + 1] * s_alpha[par][n + 1];
                accA = fmaf(wA, bf16_to_f32(tb[n * STR + tid]), accA);
                accB = fmaf(wB, bf16_to_f32(tb[(n + 1) * STR + tid]), accB);
            }
            out[(size_t)BB * DD + (size_t)b * DD + tid] = accA + accB;
        }

        __syncthreads();   // final(i) reads done -> s_f / parities reusable
    }
}

extern "C" void kernel_launch(void* const* d_in, const int* in_sizes, int n_in,
                              void* d_out, int out_size, void* d_ws, size_t ws_size,
                              hipStream_t stream) {
    const int*   seq     = (const int*)  d_in[0];
    const int*   mask    = (const int*)  d_in[1];
    const float* nodes   = (const float*)d_in[2];
    // d_in[3] = batch_size scalar (shapes compile-time fixed)
    const float* W_last  = (const float*)d_in[4];
    const float* W_seq   = (const float*)d_in[5];
    const float* b_seq   = (const float*)d_in[6];
    const float* W_alpha = (const float*)d_in[7];
    float*       out     = (float*)      d_out;

    unsigned short* wsf = (unsigned short*)d_ws;   // 64 KB combined B-fragments

    prep_w<<<16, 256, 0, stream>>>(W_seq, W_last, wsf);
    sess_attn<<<GRID, 256, 0, stream>>>(seq, mask, nodes, b_seq, W_alpha, wsf, out);
}